// Round 8
// baseline (577.837 us; speedup 1.0000x reference)
//
#include <hip/hip_runtime.h>

#define DIM 64
#define NBK 512       // node buckets per side (users / items)
#define TEPT 8        // edges per thread in bin_chunked (tile = 2048 edges)
#define TSTRIDE 1040  // table row stride in ints (1025 used, 64B-aligned rows)
#define LDSBUF 7168   // fill_node staged col entries (28 KB); mean 5860, +17 sigma

typedef unsigned int uint;
typedef unsigned short ushort;

// ---- bf16 helpers ----
__device__ __forceinline__ float bf16_lo(uint u) {
    union { uint u; float f; } c; c.u = u << 16; return c.f;
}
__device__ __forceinline__ float bf16_hi(uint u) {
    union { uint u; float f; } c; c.u = u & 0xffff0000u; return c.f;
}
__device__ __forceinline__ uint f2b(float f) {   // bf16 in low 16 bits (RNE)
    union { float f; uint u; } c; c.f = f;
    return (c.u + 0x7fffu + ((c.u >> 16) & 1u)) >> 16;
}

// f32 -> bf16, 8 elems/thread, output row pitch/offset in ushorts (rows of 64).
__global__ void cvt_bf16_pitch(const float* __restrict__ in, ushort* __restrict__ out,
                               int n8, int pitch, int off) {
    int k = blockIdx.x * blockDim.x + threadIdx.x;
    if (k >= n8) return;
    int row = k >> 3, g = k & 7;
    const float4* p = (const float4*)in + (size_t)k * 2;
    float4 a = p[0], b = p[1];
    uint4 o;
    o.x = f2b(a.x) | (f2b(a.y) << 16);
    o.y = f2b(a.z) | (f2b(a.w) << 16);
    o.z = f2b(b.x) | (f2b(b.y) << 16);
    o.w = f2b(b.z) | (f2b(b.w) << 16);
    *(uint4*)(out + (size_t)row * pitch + off + g * 8) = o;
}

// ---- CSR build, chunked-slab design, ZERO global atomics ----
// One pass over the edge list. Per tile (2048 edges -> 4096 entries):
//  - LDS per-bucket counts (1024 buckets: 512 user node-ranges + 512 item)
//  - parallel LDS exclusive scan -> bucket-grouped layout inside the tile's
//    OWN contiguous 16 KB slab (zero write amplification, no global cursors)
//  - per-tile 1025-int offset table row (coalesced)
// Entry words: user: (s % nu_pb) | t<<9 (391<2^9, t<2^17 -> 26b)
//              item: (t % ni_pb) | s<<8 (196<2^8, s<2^18 -> 26b)
__global__ __launch_bounds__(256) void bin_chunked(
        const int* __restrict__ src, const int* __restrict__ dst,
        int* __restrict__ table, uint* __restrict__ bins,
        int E, int n_users, int nu_pb, int ni_pb) {
    __shared__ int cnt[2 * NBK];
    __shared__ int lbase[2 * NBK + 1];
    __shared__ int ws[4];
    __shared__ uint ord[4096];
    for (int i = threadIdx.x; i < 2 * NBK; i += 256) cnt[i] = 0;
    __syncthreads();
    int t0 = blockIdx.x * (256 * TEPT) + threadIdx.x;
    uint st[2 * TEPT];   // packed (bucket<<12 | local offset), static idx only
    #pragma unroll
    for (int k = 0; k < TEPT; ++k) {
        int e = t0 + k * 256;
        if (e < E) {
            int s = src[e], t = dst[e];
            int bu = s / nu_pb;
            int bi = t / ni_pb;
            int ou = atomicAdd(&cnt[bu], 1);
            int oi = atomicAdd(&cnt[NBK + bi], 1);
            st[2 * k]     = ((uint)bu << 12) | (uint)ou;
            st[2 * k + 1] = ((uint)(NBK + bi) << 12) | (uint)oi;
        }
    }
    __syncthreads();
    // parallel exclusive scan of cnt[0..1024): 4 elems per thread
    {
        int c0 = threadIdx.x * 4;
        int a0 = cnt[c0], a1 = cnt[c0 + 1], a2 = cnt[c0 + 2], a3 = cnt[c0 + 3];
        int s4 = a0 + a1 + a2 + a3;
        int lane = threadIdx.x & 63, wid = threadIdx.x >> 6;
        int incl = s4;
        #pragma unroll
        for (int off = 1; off < 64; off <<= 1) {
            int t = __shfl_up(incl, off, 64);
            if (lane >= off) incl += t;
        }
        if (lane == 63) ws[wid] = incl;
        __syncthreads();
        int woff = 0;
        for (int w = 0; w < wid; ++w) woff += ws[w];
        int run = woff + incl - s4;
        lbase[c0] = run; run += a0;
        lbase[c0 + 1] = run; run += a1;
        lbase[c0 + 2] = run; run += a2;
        lbase[c0 + 3] = run; run += a3;
        if (threadIdx.x == 255) lbase[2 * NBK] = run;
    }
    __syncthreads();
    int* trow = table + (size_t)blockIdx.x * TSTRIDE;
    for (int i = threadIdx.x; i <= 2 * NBK; i += 256) trow[i] = lbase[i];
    // phase 2: re-read edges (L1-warm), place into bucket-grouped LDS
    #pragma unroll
    for (int k = 0; k < TEPT; ++k) {
        int e = t0 + k * 256;
        if (e < E) {
            int s = src[e], t = dst[e];
            uint su = st[2 * k], si = st[2 * k + 1];
            int bu = (int)(su >> 12);
            int bi = (int)(si >> 12) - NBK;
            uint wu = (uint)(s - bu * nu_pb) | ((uint)t << 9);
            uint wi = (uint)(t - bi * ni_pb) | ((uint)s << 8);
            ord[lbase[bu] + (int)(su & 4095u)] = wu;
            ord[lbase[NBK + bi] + (int)(si & 4095u)] = wi;
        }
    }
    __syncthreads();
    int tot = lbase[2 * NBK];
    uint* slab = bins + (size_t)blockIdx.x * 4096;
    for (int j = threadIdx.x; j < tot; j += 256)
        slab[j] = ord[j];
}

// Per-bucket edge totals from the per-tile table (L3-resident).
__global__ __launch_bounds__(256) void bucket_sums(
        const int* __restrict__ table, int* __restrict__ btot, int ntiles) {
    int b = blockIdx.x;   // 0..1023
    int s = 0;
    for (int t = threadIdx.x; t < ntiles; t += 256) {
        const int* row = table + (size_t)t * TSTRIDE + b;
        s += row[1] - row[0];
    }
    #pragma unroll
    for (int m = 1; m < 64; m <<= 1) s += __shfl_xor(s, m, 64);
    __shared__ int ws[4];
    int lane = threadIdx.x & 63, wid = threadIdx.x >> 6;
    if (lane == 0) ws[wid] = s;
    __syncthreads();
    if (threadIdx.x == 0) btot[b] = ws[0] + ws[1] + ws[2] + ws[3];
}

// Exclusive scan of the 1024 bucket totals -> bucket col bases. Also seals
// deg[n_nodes] = 2E.
__global__ void scan1024(const int* __restrict__ btot, int* __restrict__ bstart,
                         int* __restrict__ deg, int n_nodes, int total) {
    __shared__ int ws[16];
    int lane = threadIdx.x & 63, wid = threadIdx.x >> 6;
    int v = btot[threadIdx.x];
    int incl = v;
    #pragma unroll
    for (int off = 1; off < 64; off <<= 1) {
        int t = __shfl_up(incl, off, 64);
        if (lane >= off) incl += t;
    }
    if (lane == 63) ws[wid] = incl;
    __syncthreads();
    int woff = 0;
    for (int w = 0; w < wid; ++w) woff += ws[w];
    bstart[threadIdx.x] = woff + incl - v;
    if ((int)threadIdx.x == 1023) {
        bstart[1024] = total;
        deg[n_nodes] = total;
    }
}

// One block per bucket (1024 blocks), exclusive node-range ownership.
// Pass 1: per-node degree histogram via LDS atomics over the bucket's slab
// slices; in-LDS chunked block scan -> per-node exclusive prefix; deg written
// DENSE. Pass 2: placement via LDS cursor atomics into a staged 28 KB col
// segment, written out dense -> zero write amplification. ~30 KB LDS/block
// -> 4-5 blocks/CU (vs 2 at r7) for latency hiding.
__global__ __launch_bounds__(256) void fill_node(
        const uint* __restrict__ bins, const int* __restrict__ table,
        const int* __restrict__ bstart, int* __restrict__ deg,
        int* __restrict__ col,
        int n_users, int n_items, int ntiles, int nu_pb, int ni_pb) {
    __shared__ int cur[400];
    __shared__ int ws[4];
    __shared__ int lbuf[LDSBUF];
    int b = blockIdx.x;
    bool user = b < NBK;
    int bb = user ? b : b - NBK;
    int npb = user ? nu_pb : ni_pb;
    int ncnt = user ? n_users : n_items;
    int node0 = bb * npb;
    int nn = min(npb, ncnt - node0);
    if (nn <= 0) return;
    int idx0 = (user ? 0 : n_users) + node0;
    int colbase = bstart[b];
    int nedge = bstart[b + 1] - colbase;
    uint mask = user ? 511u : 255u;
    int shift = user ? 9 : 8;

    for (int i = threadIdx.x; i < nn; i += 256) cur[i] = 0;
    __syncthreads();
    // pass 1: per-node histogram (LDS atomics only)
    for (int t = threadIdx.x; t < ntiles; t += 256) {
        const int* row = table + (size_t)t * TSTRIDE + b;
        int a = row[0], e2 = row[1];
        const uint* slab = bins + (size_t)t * 4096;
        for (int j = a; j < e2; ++j)
            atomicAdd(&cur[(int)(slab[j] & mask)], 1);
    }
    __syncthreads();
    // chunked exclusive scan of cur[0..nn): thread chunk sums -> wave scan
    int CH = (nn + 255) >> 8;
    int c0 = threadIdx.x * CH;
    int s = 0;
    for (int i = 0; i < CH; ++i) {
        int idx = c0 + i;
        if (idx < nn) s += cur[idx];
    }
    int lane = threadIdx.x & 63, wid = threadIdx.x >> 6;
    int incl = s;
    #pragma unroll
    for (int off = 1; off < 64; off <<= 1) {
        int t = __shfl_up(incl, off, 64);
        if (lane >= off) incl += t;
    }
    if (lane == 63) ws[wid] = incl;
    __syncthreads();
    int woff = 0;
    for (int w = 0; w < wid; ++w) woff += ws[w];
    int running = woff + incl - s;   // exclusive prefix of this thread's chunk
    for (int i = 0; i < CH; ++i) {
        int idx = c0 + i;
        if (idx < nn) {
            int c = cur[idx];
            cur[idx] = running;                  // local cursor start
            deg[idx0 + idx] = colbase + running; // dense deg write
            running += c;
        }
    }
    __syncthreads();
    // pass 2: placement
    if (nedge <= LDSBUF) {
        for (int t = threadIdx.x; t < ntiles; t += 256) {
            const int* row = table + (size_t)t * TSTRIDE + b;
            int a = row[0], e2 = row[1];
            const uint* slab = bins + (size_t)t * 4096;
            for (int j = a; j < e2; ++j) {
                uint w = slab[j];
                int p = atomicAdd(&cur[(int)(w & mask)], 1);
                lbuf[p] = (int)(w >> shift);
            }
        }
        __syncthreads();
        for (int j = threadIdx.x; j < nedge; j += 256)
            col[colbase + j] = lbuf[j];
    } else {  // statistically unreachable fallback (bucket > LDSBUF edges)
        for (int t = threadIdx.x; t < ntiles; t += 256) {
            const int* row = table + (size_t)t * TSTRIDE + b;
            int a = row[0], e2 = row[1];
            const uint* slab = bins + (size_t)t * 4096;
            for (int j = a; j < e2; ++j) {
                uint w = slab[j];
                int p = atomicAdd(&cur[(int)(w & mask)], 1);
                col[colbase + p] = (int)(w >> shift);
            }
        }
    }
}

// ---- 128B-row gather (one wave per node; r=lane>>3 row slot, c=lane&7 chunk).
// ends[node] = start of node+1 (pass deg+1); ends[node-1] = start of node.
// COMBINE=0: bf16 out at (ob_pitch, ob_off).
// COMBINE=1: outf = (x0 + x1 + mean)/3, x1 bf16 at (x1_pitch, x1_off).
// NOTE: outf may alias x1's buffer (same row, same wave) — data dependency
// (store value uses loaded x1) keeps this safe; no __restrict__ on those.
template <int COMBINE>
__global__ __launch_bounds__(256) void gather128(
        const ushort* __restrict__ feat,
        const int* __restrict__ ends,
        const int* __restrict__ col,
        const float* __restrict__ x0,
        const ushort* x1, int x1_pitch, int x1_off,
        float* outf,
        ushort* outb, int ob_pitch, int ob_off,
        int n) {
    int node = blockIdx.x * 4 + (threadIdx.x >> 6);
    if (node >= n) return;
    int lane = threadIdx.x & 63;
    int r = lane >> 3, c = lane & 7;
    int beg = ends[node - 1];
    int end = ends[node];
    const ushort* fbase = feat + c * 8;

    float acc[8];
    #pragma unroll
    for (int j = 0; j < 8; ++j) acc[j] = 0.0f;

    for (int e = beg; e < end; e += 16) {
        int i0 = e + r, i1 = e + 8 + r;
        bool ok0 = i0 < end, ok1 = i1 < end;
        int nb0 = col[ok0 ? i0 : beg];
        int nb1 = col[ok1 ? i1 : beg];
        uint4 v0 = *(const uint4*)(fbase + (size_t)nb0 * DIM);
        uint4 v1 = *(const uint4*)(fbase + (size_t)nb1 * DIM);
        if (ok0) {
            acc[0] += bf16_lo(v0.x); acc[1] += bf16_hi(v0.x);
            acc[2] += bf16_lo(v0.y); acc[3] += bf16_hi(v0.y);
            acc[4] += bf16_lo(v0.z); acc[5] += bf16_hi(v0.z);
            acc[6] += bf16_lo(v0.w); acc[7] += bf16_hi(v0.w);
        }
        if (ok1) {
            acc[0] += bf16_lo(v1.x); acc[1] += bf16_hi(v1.x);
            acc[2] += bf16_lo(v1.y); acc[3] += bf16_hi(v1.y);
            acc[4] += bf16_lo(v1.z); acc[5] += bf16_hi(v1.z);
            acc[6] += bf16_lo(v1.w); acc[7] += bf16_hi(v1.w);
        }
    }
    #pragma unroll
    for (int m = 8; m < 64; m <<= 1) {
        #pragma unroll
        for (int j = 0; j < 8; ++j) acc[j] += __shfl_xor(acc[j], m, 64);
    }
    if (r == 0) {
        int d = end - beg;
        float inv = (d > 0) ? 1.0f / (float)d : 0.0f;
        if (COMBINE) {
            size_t base = (size_t)node * DIM + c * 8;
            float4 xa = *(const float4*)(x0 + base);
            float4 xb = *(const float4*)(x0 + base + 4);
            uint4  xq = *(const uint4*)(x1 + (size_t)node * x1_pitch + x1_off + c * 8);
            float4 oa, ob;
            oa.x = (xa.x + bf16_lo(xq.x) + acc[0] * inv) * (1.0f / 3.0f);
            oa.y = (xa.y + bf16_hi(xq.x) + acc[1] * inv) * (1.0f / 3.0f);
            oa.z = (xa.z + bf16_lo(xq.y) + acc[2] * inv) * (1.0f / 3.0f);
            oa.w = (xa.w + bf16_hi(xq.y) + acc[3] * inv) * (1.0f / 3.0f);
            ob.x = (xb.x + bf16_lo(xq.z) + acc[4] * inv) * (1.0f / 3.0f);
            ob.y = (xb.y + bf16_hi(xq.z) + acc[5] * inv) * (1.0f / 3.0f);
            ob.z = (xb.z + bf16_lo(xq.w) + acc[6] * inv) * (1.0f / 3.0f);
            ob.w = (xb.w + bf16_hi(xq.w) + acc[7] * inv) * (1.0f / 3.0f);
            *(float4*)(outf + base)     = oa;
            *(float4*)(outf + base + 4) = ob;
        } else {
            uint4 o;
            o.x = f2b(acc[0] * inv) | (f2b(acc[1] * inv) << 16);
            o.y = f2b(acc[2] * inv) | (f2b(acc[3] * inv) << 16);
            o.z = f2b(acc[4] * inv) | (f2b(acc[5] * inv) << 16);
            o.w = f2b(acc[6] * inv) | (f2b(acc[7] * inv) << 16);
            *(uint4*)(outb + (size_t)node * ob_pitch + ob_off + c * 8) = o;
        }
    }
}

// ---- 256B-row fused item pass: feat = u01 (u0|u1 interleaved, pitch 128).
// Computes i1 = mean(u0-nbrs), i2 = mean(u1-nbrs) in ONE col walk.
// outf = (x0 + i1 + i2)/3 (f32), outb = bf16(i1) (dense pitch 64).
// 4 row-loads in flight per iteration (mean degree 30 -> ~2 iters); per-lane
// accumulation order identical to the 2-load version (bitwise-same results).
__global__ __launch_bounds__(256) void gather256_combine(
        const ushort* __restrict__ feat,
        const int* __restrict__ ends,
        const int* __restrict__ col,
        const float* __restrict__ x0,
        float* __restrict__ outf,
        ushort* __restrict__ outb,
        int n) {
    int node = blockIdx.x * 4 + (threadIdx.x >> 6);
    if (node >= n) return;
    int lane = threadIdx.x & 63;
    int c = lane & 15, r = lane >> 4;          // c: 16B chunk of 256B row
    int beg = ends[node - 1];
    int end = ends[node];
    const ushort* fbase = feat + c * 8;

    float acc[8];
    #pragma unroll
    for (int j = 0; j < 8; ++j) acc[j] = 0.0f;

    for (int e = beg; e < end; e += 16) {
        int i0 = e + r, i1 = e + 4 + r, i2 = e + 8 + r, i3 = e + 12 + r;
        bool ok0 = i0 < end, ok1 = i1 < end, ok2 = i2 < end, ok3 = i3 < end;
        int nb0 = col[ok0 ? i0 : beg];
        int nb1 = col[ok1 ? i1 : beg];
        int nb2 = col[ok2 ? i2 : beg];
        int nb3 = col[ok3 ? i3 : beg];
        uint4 v0 = *(const uint4*)(fbase + (size_t)nb0 * 128);
        uint4 v1 = *(const uint4*)(fbase + (size_t)nb1 * 128);
        uint4 v2 = *(const uint4*)(fbase + (size_t)nb2 * 128);
        uint4 v3 = *(const uint4*)(fbase + (size_t)nb3 * 128);
        if (ok0) {
            acc[0] += bf16_lo(v0.x); acc[1] += bf16_hi(v0.x);
            acc[2] += bf16_lo(v0.y); acc[3] += bf16_hi(v0.y);
            acc[4] += bf16_lo(v0.z); acc[5] += bf16_hi(v0.z);
            acc[6] += bf16_lo(v0.w); acc[7] += bf16_hi(v0.w);
        }
        if (ok1) {
            acc[0] += bf16_lo(v1.x); acc[1] += bf16_hi(v1.x);
            acc[2] += bf16_lo(v1.y); acc[3] += bf16_hi(v1.y);
            acc[4] += bf16_lo(v1.z); acc[5] += bf16_hi(v1.z);
            acc[6] += bf16_lo(v1.w); acc[7] += bf16_hi(v1.w);
        }
        if (ok2) {
            acc[0] += bf16_lo(v2.x); acc[1] += bf16_hi(v2.x);
            acc[2] += bf16_lo(v2.y); acc[3] += bf16_hi(v2.y);
            acc[4] += bf16_lo(v2.z); acc[5] += bf16_hi(v2.z);
            acc[6] += bf16_lo(v2.w); acc[7] += bf16_hi(v2.w);
        }
        if (ok3) {
            acc[0] += bf16_lo(v3.x); acc[1] += bf16_hi(v3.x);
            acc[2] += bf16_lo(v3.y); acc[3] += bf16_hi(v3.y);
            acc[4] += bf16_lo(v3.z); acc[5] += bf16_hi(v3.z);
            acc[6] += bf16_lo(v3.w); acc[7] += bf16_hi(v3.w);
        }
    }
    // fold the 4 r-slots (lane bits 4,5)
    #pragma unroll
    for (int m = 16; m < 64; m <<= 1) {
        #pragma unroll
        for (int j = 0; j < 8; ++j) acc[j] += __shfl_xor(acc[j], m, 64);
    }
    // partner exchange: lane c (<8, u0-part) pairs with lane c+8 (u1-part, same elems)
    float b8[8];
    #pragma unroll
    for (int j = 0; j < 8; ++j) b8[j] = __shfl_xor(acc[j], 8, 64);

    if (r == 0 && c < 8) {
        int d = end - beg;
        float inv = (d > 0) ? 1.0f / (float)d : 0.0f;
        size_t base = (size_t)node * DIM + c * 8;
        float4 xa = *(const float4*)(x0 + base);
        float4 xb = *(const float4*)(x0 + base + 4);
        float i1v[8];
        #pragma unroll
        for (int j = 0; j < 8; ++j) i1v[j] = acc[j] * inv;
        float4 oa, ob;
        oa.x = (xa.x + i1v[0] + b8[0] * inv) * (1.0f / 3.0f);
        oa.y = (xa.y + i1v[1] + b8[1] * inv) * (1.0f / 3.0f);
        oa.z = (xa.z + i1v[2] + b8[2] * inv) * (1.0f / 3.0f);
        oa.w = (xa.w + i1v[3] + b8[3] * inv) * (1.0f / 3.0f);
        ob.x = (xb.x + i1v[4] + b8[4] * inv) * (1.0f / 3.0f);
        ob.y = (xb.y + i1v[5] + b8[5] * inv) * (1.0f / 3.0f);
        ob.z = (xb.z + i1v[6] + b8[6] * inv) * (1.0f / 3.0f);
        ob.w = (xb.w + i1v[7] + b8[7] * inv) * (1.0f / 3.0f);
        *(float4*)(outf + base)     = oa;
        *(float4*)(outf + base + 4) = ob;
        uint4 q;
        q.x = f2b(i1v[0]) | (f2b(i1v[1]) << 16);
        q.y = f2b(i1v[2]) | (f2b(i1v[3]) << 16);
        q.z = f2b(i1v[4]) | (f2b(i1v[5]) << 16);
        q.w = f2b(i1v[6]) | (f2b(i1v[7]) << 16);
        *(uint4*)(outb + base) = q;
    }
}

extern "C" void kernel_launch(void* const* d_in, const int* in_sizes, int n_in,
                              void* d_out, int out_size, void* d_ws, size_t ws_size,
                              hipStream_t stream) {
    const float* u0  = (const float*)d_in[0];
    const float* i0  = (const float*)d_in[1];
    const int*   src = (const int*)d_in[2];
    const int*   dst = (const int*)d_in[3];

    const int n_users = in_sizes[0] / DIM;   // 200000
    const int n_items = in_sizes[1] / DIM;   // 100000
    const int E       = in_sizes[2];         // 3000000
    const int n_nodes = n_users + n_items;
    const int nu_pb   = (n_users + NBK - 1) / NBK;   // 391 (< 2^9: packing req)
    const int ni_pb   = (n_items + NBK - 1) / NBK;   // 196 (< 2^8: packing req)

    const size_t u_elems = (size_t)n_users * DIM;
    const size_t i_elems = (size_t)n_items * DIM;

    // Workspace (~38 MB):
    //   deg[n_nodes+1] | btot[1024] | bstart[1025+pad] | col[2E] | ib[i_elems bf16]
    int* deg    = (int*)d_ws;
    int* btot   = deg + n_nodes + 1;
    int* bstart = btot + 1024;
    int* col    = bstart + 1028;
    ushort* ib  = (ushort*)(col + 2 * (size_t)E);  // i0 bf16, later i1 bf16

    // d_out: user region doubles as the per-tile offset table (6.1 MB) during
    // CSR build, then as u01 (u0|u1 interleaved bf16, 256B rows). item region
    // (out_i, 25.6 MB) doubles as the slab array (23.4 MB) — dead until
    // gather256_combine writes it.
    float* out_u = (float*)d_out;
    float* out_i = out_u + u_elems;
    ushort* u01  = (ushort*)d_out;         // exactly overlays out_u (51.2 MB)
    int*   table = (int*)d_out;
    uint*  bins  = (uint*)out_i;

    const int BLK = 256;
    const int ntiles = (E + BLK * TEPT - 1) / (BLK * TEPT);   // 1465

    // ---- CSR build: bin -> bucket sums -> bucket scan -> fill(deg+col) ----
    bin_chunked<<<ntiles, BLK, 0, stream>>>(src, dst, table, bins,
                                            E, n_users, nu_pb, ni_pb);
    bucket_sums<<<2 * NBK, BLK, 0, stream>>>(table, btot, ntiles);
    scan1024<<<1, 1024, 0, stream>>>(btot, bstart, deg, n_nodes, 2 * E);
    fill_node<<<2 * NBK, BLK, 0, stream>>>(bins, table, bstart, deg, col,
                                           n_users, n_items, ntiles, nu_pb, ni_pb);
    // deg holds exclusive starts (users then items), deg[n_nodes] = 2E.

    // ---- stage bf16 (table/bins regions are dead from here on) ----
    cvt_bf16_pitch<<<(int)((u_elems / 8 + BLK - 1) / BLK), BLK, 0, stream>>>(
        u0, u01, (int)(u_elems / 8), 128, 0);
    cvt_bf16_pitch<<<(int)((i_elems / 8 + BLK - 1) / BLK), BLK, 0, stream>>>(
        i0, ib, (int)(i_elems / 8), 64, 0);

    const int ug = (n_users + 3) / 4;
    const int ig = (n_items + 3) / 4;

    // ---- Pass A: u1 = mean(i0-nbrs) -> u01 odd halves (bf16) ----
    gather128<0><<<ug, BLK, 0, stream>>>(ib, deg + 1, col, nullptr,
                                         nullptr, 0, 0, nullptr,
                                         u01, 128, 64, n_users);

    // ---- Pass C: fused item pass: out_i = (i0 + i1 + i2)/3, ib <- bf16(i1) ----
    gather256_combine<<<ig, BLK, 0, stream>>>(u01, deg + n_users + 1, col,
                                              i0, out_i, ib, n_items);

    // ---- Pass D: out_u = (u0 + u1 + mean(i1-nbrs))/3 (u1 from u01 odd) ----
    gather128<1><<<ug, BLK, 0, stream>>>(ib, deg + 1, col, u0,
                                         u01, 128, 64, out_u,
                                         nullptr, 0, 0, n_users);
}

// Round 9
// 575.425 us; speedup vs baseline: 1.0042x; 1.0042x over previous
//
#include <hip/hip_runtime.h>

#define DIM 64
#define NBK 512       // node buckets per side (users / items)
#define TEPT 8        // edges per thread in bin_chunked (tile = 2048 edges)
#define TSTRIDE 1040  // table row stride in ints (1025 used, 64B-aligned rows)
#define LDSBUF 7168   // fill_place staged col entries (28 KB); mean 5860, +17 sigma

typedef unsigned int uint;
typedef unsigned short ushort;

// ---- bf16 helpers ----
__device__ __forceinline__ float bf16_lo(uint u) {
    union { uint u; float f; } c; c.u = u << 16; return c.f;
}
__device__ __forceinline__ float bf16_hi(uint u) {
    union { uint u; float f; } c; c.u = u & 0xffff0000u; return c.f;
}
__device__ __forceinline__ uint f2b(float f) {   // bf16 in low 16 bits (RNE)
    union { float f; uint u; } c; c.f = f;
    return (c.u + 0x7fffu + ((c.u >> 16) & 1u)) >> 16;
}

// f32 -> bf16, 8 elems/thread, output row pitch/offset in ushorts (rows of 64).
__global__ void cvt_bf16_pitch(const float* __restrict__ in, ushort* __restrict__ out,
                               int n8, int pitch, int off) {
    int k = blockIdx.x * blockDim.x + threadIdx.x;
    if (k >= n8) return;
    int row = k >> 3, g = k & 7;
    const float4* p = (const float4*)in + (size_t)k * 2;
    float4 a = p[0], b = p[1];
    uint4 o;
    o.x = f2b(a.x) | (f2b(a.y) << 16);
    o.y = f2b(a.z) | (f2b(a.w) << 16);
    o.z = f2b(b.x) | (f2b(b.y) << 16);
    o.w = f2b(b.z) | (f2b(b.w) << 16);
    *(uint4*)(out + (size_t)row * pitch + off + g * 8) = o;
}

// ---- CSR build, chunked-slab design, ZERO global atomics ----
// One pass over the edge list. Per tile (2048 edges -> 4096 entries):
//  - LDS per-bucket counts (1024 buckets: 512 user node-ranges + 512 item)
//  - parallel LDS exclusive scan -> bucket-grouped layout inside the tile's
//    OWN contiguous 16 KB slab (zero write amplification, no global cursors)
//  - per-tile 1025-int offset table row (coalesced)
// Entry words: user: (s % nu_pb) | t<<9 (391<2^9, t<2^17 -> 26b)
//              item: (t % ni_pb) | s<<8 (196<2^8, s<2^18 -> 26b)
__global__ __launch_bounds__(256) void bin_chunked(
        const int* __restrict__ src, const int* __restrict__ dst,
        int* __restrict__ table, uint* __restrict__ bins,
        int E, int n_users, int nu_pb, int ni_pb) {
    __shared__ int cnt[2 * NBK];
    __shared__ int lbase[2 * NBK + 1];
    __shared__ int ws[4];
    __shared__ uint ord[4096];
    for (int i = threadIdx.x; i < 2 * NBK; i += 256) cnt[i] = 0;
    __syncthreads();
    int t0 = blockIdx.x * (256 * TEPT) + threadIdx.x;
    uint st[2 * TEPT];   // packed (bucket<<12 | local offset), static idx only
    #pragma unroll
    for (int k = 0; k < TEPT; ++k) {
        int e = t0 + k * 256;
        if (e < E) {
            int s = src[e], t = dst[e];
            int bu = s / nu_pb;
            int bi = t / ni_pb;
            int ou = atomicAdd(&cnt[bu], 1);
            int oi = atomicAdd(&cnt[NBK + bi], 1);
            st[2 * k]     = ((uint)bu << 12) | (uint)ou;
            st[2 * k + 1] = ((uint)(NBK + bi) << 12) | (uint)oi;
        }
    }
    __syncthreads();
    // parallel exclusive scan of cnt[0..1024): 4 elems per thread
    {
        int c0 = threadIdx.x * 4;
        int a0 = cnt[c0], a1 = cnt[c0 + 1], a2 = cnt[c0 + 2], a3 = cnt[c0 + 3];
        int s4 = a0 + a1 + a2 + a3;
        int lane = threadIdx.x & 63, wid = threadIdx.x >> 6;
        int incl = s4;
        #pragma unroll
        for (int off = 1; off < 64; off <<= 1) {
            int t = __shfl_up(incl, off, 64);
            if (lane >= off) incl += t;
        }
        if (lane == 63) ws[wid] = incl;
        __syncthreads();
        int woff = 0;
        for (int w = 0; w < wid; ++w) woff += ws[w];
        int run = woff + incl - s4;
        lbase[c0] = run; run += a0;
        lbase[c0 + 1] = run; run += a1;
        lbase[c0 + 2] = run; run += a2;
        lbase[c0 + 3] = run; run += a3;
        if (threadIdx.x == 255) lbase[2 * NBK] = run;
    }
    __syncthreads();
    int* trow = table + (size_t)blockIdx.x * TSTRIDE;
    for (int i = threadIdx.x; i <= 2 * NBK; i += 256) trow[i] = lbase[i];
    // phase 2: re-read edges (L1-warm), place into bucket-grouped LDS
    #pragma unroll
    for (int k = 0; k < TEPT; ++k) {
        int e = t0 + k * 256;
        if (e < E) {
            int s = src[e], t = dst[e];
            uint su = st[2 * k], si = st[2 * k + 1];
            int bu = (int)(su >> 12);
            int bi = (int)(si >> 12) - NBK;
            uint wu = (uint)(s - bu * nu_pb) | ((uint)t << 9);
            uint wi = (uint)(t - bi * ni_pb) | ((uint)s << 8);
            ord[lbase[bu] + (int)(su & 4095u)] = wu;
            ord[lbase[NBK + bi] + (int)(si & 4095u)] = wi;
        }
    }
    __syncthreads();
    int tot = lbase[2 * NBK];
    uint* slab = bins + (size_t)blockIdx.x * 4096;
    for (int j = threadIdx.x; j < tot; j += 256)
        slab[j] = ord[j];
}

// Per-bucket edge totals from the per-tile table (L3-resident).
__global__ __launch_bounds__(256) void bucket_sums(
        const int* __restrict__ table, int* __restrict__ btot, int ntiles) {
    int b = blockIdx.x;   // 0..1023
    int s = 0;
    for (int t = threadIdx.x; t < ntiles; t += 256) {
        const int* row = table + (size_t)t * TSTRIDE + b;
        s += row[1] - row[0];
    }
    #pragma unroll
    for (int m = 1; m < 64; m <<= 1) s += __shfl_xor(s, m, 64);
    __shared__ int ws[4];
    int lane = threadIdx.x & 63, wid = threadIdx.x >> 6;
    if (lane == 0) ws[wid] = s;
    __syncthreads();
    if (threadIdx.x == 0) btot[b] = ws[0] + ws[1] + ws[2] + ws[3];
}

// Exclusive scan of the 1024 bucket totals -> bucket col bases. Also seals
// deg[n_nodes] = 2E.
__global__ void scan1024(const int* __restrict__ btot, int* __restrict__ bstart,
                         int* __restrict__ deg, int n_nodes, int total) {
    __shared__ int ws[16];
    int lane = threadIdx.x & 63, wid = threadIdx.x >> 6;
    int v = btot[threadIdx.x];
    int incl = v;
    #pragma unroll
    for (int off = 1; off < 64; off <<= 1) {
        int t = __shfl_up(incl, off, 64);
        if (lane >= off) incl += t;
    }
    if (lane == 63) ws[wid] = incl;
    __syncthreads();
    int woff = 0;
    for (int w = 0; w < wid; ++w) woff += ws[w];
    bstart[threadIdx.x] = woff + incl - v;
    if ((int)threadIdx.x == 1023) {
        bstart[1024] = total;
        deg[n_nodes] = total;
    }
}

// Histogram half of the fill (split from fill_node r8): tiny LDS (1.6 KB)
// -> 8+ blocks/CU for the latency-bound table/slab walk. Per-node degree
// histogram via LDS atomics; in-LDS chunked scan; deg written DENSE.
__global__ __launch_bounds__(256) void fill_hist(
        const uint* __restrict__ bins, const int* __restrict__ table,
        const int* __restrict__ bstart, int* __restrict__ deg,
        int n_users, int n_items, int ntiles, int nu_pb, int ni_pb) {
    __shared__ int cur[400];
    __shared__ int ws[4];
    int b = blockIdx.x;
    bool user = b < NBK;
    int bb = user ? b : b - NBK;
    int npb = user ? nu_pb : ni_pb;
    int ncnt = user ? n_users : n_items;
    int node0 = bb * npb;
    int nn = min(npb, ncnt - node0);
    if (nn <= 0) return;
    int idx0 = (user ? 0 : n_users) + node0;
    int colbase = bstart[b];
    uint mask = user ? 511u : 255u;

    for (int i = threadIdx.x; i < nn; i += 256) cur[i] = 0;
    __syncthreads();
    for (int t = threadIdx.x; t < ntiles; t += 256) {
        const int* row = table + (size_t)t * TSTRIDE + b;
        int a = row[0], e2 = row[1];
        const uint* slab = bins + (size_t)t * 4096;
        for (int j = a; j < e2; ++j)
            atomicAdd(&cur[(int)(slab[j] & mask)], 1);
    }
    __syncthreads();
    // chunked exclusive scan of cur[0..nn) -> dense deg write
    int CH = (nn + 255) >> 8;
    int c0 = threadIdx.x * CH;
    int s = 0;
    for (int i = 0; i < CH; ++i) {
        int idx = c0 + i;
        if (idx < nn) s += cur[idx];
    }
    int lane = threadIdx.x & 63, wid = threadIdx.x >> 6;
    int incl = s;
    #pragma unroll
    for (int off = 1; off < 64; off <<= 1) {
        int t = __shfl_up(incl, off, 64);
        if (lane >= off) incl += t;
    }
    if (lane == 63) ws[wid] = incl;
    __syncthreads();
    int woff = 0;
    for (int w = 0; w < wid; ++w) woff += ws[w];
    int running = woff + incl - s;
    for (int i = 0; i < CH; ++i) {
        int idx = c0 + i;
        if (idx < nn) {
            deg[idx0 + idx] = colbase + running;
            running += cur[idx];
        }
    }
}

// Placement half: local cursors rebuilt from deg (dense, L2-hot), entries
// placed via LDS cursor atomics into a staged 28 KB col segment, written out
// dense -> zero write amplification.
__global__ __launch_bounds__(256) void fill_place(
        const uint* __restrict__ bins, const int* __restrict__ table,
        const int* __restrict__ bstart, const int* __restrict__ deg,
        int* __restrict__ col,
        int n_users, int n_items, int ntiles, int nu_pb, int ni_pb) {
    __shared__ int cur[400];
    __shared__ int lbuf[LDSBUF];
    int b = blockIdx.x;
    bool user = b < NBK;
    int bb = user ? b : b - NBK;
    int npb = user ? nu_pb : ni_pb;
    int ncnt = user ? n_users : n_items;
    int node0 = bb * npb;
    int nn = min(npb, ncnt - node0);
    if (nn <= 0) return;
    int idx0 = (user ? 0 : n_users) + node0;
    int colbase = bstart[b];
    int nedge = bstart[b + 1] - colbase;
    uint mask = user ? 511u : 255u;
    int shift = user ? 9 : 8;

    for (int i = threadIdx.x; i < nn; i += 256)
        cur[i] = deg[idx0 + i] - colbase;
    __syncthreads();
    if (nedge <= LDSBUF) {
        for (int t = threadIdx.x; t < ntiles; t += 256) {
            const int* row = table + (size_t)t * TSTRIDE + b;
            int a = row[0], e2 = row[1];
            const uint* slab = bins + (size_t)t * 4096;
            for (int j = a; j < e2; ++j) {
                uint w = slab[j];
                int p = atomicAdd(&cur[(int)(w & mask)], 1);
                lbuf[p] = (int)(w >> shift);
            }
        }
        __syncthreads();
        for (int j = threadIdx.x; j < nedge; j += 256)
            col[colbase + j] = lbuf[j];
    } else {  // statistically unreachable fallback (bucket > LDSBUF edges)
        for (int t = threadIdx.x; t < ntiles; t += 256) {
            const int* row = table + (size_t)t * TSTRIDE + b;
            int a = row[0], e2 = row[1];
            const uint* slab = bins + (size_t)t * 4096;
            for (int j = a; j < e2; ++j) {
                uint w = slab[j];
                int p = atomicAdd(&cur[(int)(w & mask)], 1);
                col[colbase + p] = (int)(w >> shift);
            }
        }
    }
}

// ---- 128B-row gather (one wave per node; r=lane>>3 row slot, c=lane&7 chunk).
// 4 row-loads in flight (slots r, 8+r, 16+r, 24+r; mean degree 15 -> 1 iter).
// Masked slots load col[beg] -> wave-broadcast single line (cheap). Per-lane
// accumulation order identical to the 2-deep version (bitwise-same results).
// ends[node] = start of node+1 (pass deg+1); ends[node-1] = start of node.
// COMBINE=0: bf16 out at (ob_pitch, ob_off).
// COMBINE=1: outf = (x0 + x1 + mean)/3, x1 bf16 at (x1_pitch, x1_off).
// NOTE: outf may alias x1's buffer (same row, same wave) — data dependency
// (store value uses loaded x1) keeps this safe; no __restrict__ on those.
template <int COMBINE>
__global__ __launch_bounds__(256) void gather128(
        const ushort* __restrict__ feat,
        const int* __restrict__ ends,
        const int* __restrict__ col,
        const float* __restrict__ x0,
        const ushort* x1, int x1_pitch, int x1_off,
        float* outf,
        ushort* outb, int ob_pitch, int ob_off,
        int n) {
    int node = blockIdx.x * 4 + (threadIdx.x >> 6);
    if (node >= n) return;
    int lane = threadIdx.x & 63;
    int r = lane >> 3, c = lane & 7;
    int beg = ends[node - 1];
    int end = ends[node];
    const ushort* fbase = feat + c * 8;

    float acc[8];
    #pragma unroll
    for (int j = 0; j < 8; ++j) acc[j] = 0.0f;

    for (int e = beg; e < end; e += 32) {
        int i0 = e + r, i1 = e + 8 + r, i2 = e + 16 + r, i3 = e + 24 + r;
        bool ok0 = i0 < end, ok1 = i1 < end, ok2 = i2 < end, ok3 = i3 < end;
        int nb0 = col[ok0 ? i0 : beg];
        int nb1 = col[ok1 ? i1 : beg];
        int nb2 = col[ok2 ? i2 : beg];
        int nb3 = col[ok3 ? i3 : beg];
        uint4 v0 = *(const uint4*)(fbase + (size_t)nb0 * DIM);
        uint4 v1 = *(const uint4*)(fbase + (size_t)nb1 * DIM);
        uint4 v2 = *(const uint4*)(fbase + (size_t)nb2 * DIM);
        uint4 v3 = *(const uint4*)(fbase + (size_t)nb3 * DIM);
        if (ok0) {
            acc[0] += bf16_lo(v0.x); acc[1] += bf16_hi(v0.x);
            acc[2] += bf16_lo(v0.y); acc[3] += bf16_hi(v0.y);
            acc[4] += bf16_lo(v0.z); acc[5] += bf16_hi(v0.z);
            acc[6] += bf16_lo(v0.w); acc[7] += bf16_hi(v0.w);
        }
        if (ok1) {
            acc[0] += bf16_lo(v1.x); acc[1] += bf16_hi(v1.x);
            acc[2] += bf16_lo(v1.y); acc[3] += bf16_hi(v1.y);
            acc[4] += bf16_lo(v1.z); acc[5] += bf16_hi(v1.z);
            acc[6] += bf16_lo(v1.w); acc[7] += bf16_hi(v1.w);
        }
        if (ok2) {
            acc[0] += bf16_lo(v2.x); acc[1] += bf16_hi(v2.x);
            acc[2] += bf16_lo(v2.y); acc[3] += bf16_hi(v2.y);
            acc[4] += bf16_lo(v2.z); acc[5] += bf16_hi(v2.z);
            acc[6] += bf16_lo(v2.w); acc[7] += bf16_hi(v2.w);
        }
        if (ok3) {
            acc[0] += bf16_lo(v3.x); acc[1] += bf16_hi(v3.x);
            acc[2] += bf16_lo(v3.y); acc[3] += bf16_hi(v3.y);
            acc[4] += bf16_lo(v3.z); acc[5] += bf16_hi(v3.z);
            acc[6] += bf16_lo(v3.w); acc[7] += bf16_hi(v3.w);
        }
    }
    #pragma unroll
    for (int m = 8; m < 64; m <<= 1) {
        #pragma unroll
        for (int j = 0; j < 8; ++j) acc[j] += __shfl_xor(acc[j], m, 64);
    }
    if (r == 0) {
        int d = end - beg;
        float inv = (d > 0) ? 1.0f / (float)d : 0.0f;
        if (COMBINE) {
            size_t base = (size_t)node * DIM + c * 8;
            float4 xa = *(const float4*)(x0 + base);
            float4 xb = *(const float4*)(x0 + base + 4);
            uint4  xq = *(const uint4*)(x1 + (size_t)node * x1_pitch + x1_off + c * 8);
            float4 oa, ob;
            oa.x = (xa.x + bf16_lo(xq.x) + acc[0] * inv) * (1.0f / 3.0f);
            oa.y = (xa.y + bf16_hi(xq.x) + acc[1] * inv) * (1.0f / 3.0f);
            oa.z = (xa.z + bf16_lo(xq.y) + acc[2] * inv) * (1.0f / 3.0f);
            oa.w = (xa.w + bf16_hi(xq.y) + acc[3] * inv) * (1.0f / 3.0f);
            ob.x = (xb.x + bf16_lo(xq.z) + acc[4] * inv) * (1.0f / 3.0f);
            ob.y = (xb.y + bf16_hi(xq.z) + acc[5] * inv) * (1.0f / 3.0f);
            ob.z = (xb.z + bf16_lo(xq.w) + acc[6] * inv) * (1.0f / 3.0f);
            ob.w = (xb.w + bf16_hi(xq.w) + acc[7] * inv) * (1.0f / 3.0f);
            *(float4*)(outf + base)     = oa;
            *(float4*)(outf + base + 4) = ob;
        } else {
            uint4 o;
            o.x = f2b(acc[0] * inv) | (f2b(acc[1] * inv) << 16);
            o.y = f2b(acc[2] * inv) | (f2b(acc[3] * inv) << 16);
            o.z = f2b(acc[4] * inv) | (f2b(acc[5] * inv) << 16);
            o.w = f2b(acc[6] * inv) | (f2b(acc[7] * inv) << 16);
            *(uint4*)(outb + (size_t)node * ob_pitch + ob_off + c * 8) = o;
        }
    }
}

// ---- 256B-row fused item pass: feat = u01 (u0|u1 interleaved, pitch 128).
// Computes i1 = mean(u0-nbrs), i2 = mean(u1-nbrs) in ONE col walk.
// outf = (x0 + i1 + i2)/3 (f32), outb = bf16(i1) (dense pitch 64).
// 4 row-loads in flight per iteration (mean degree 30 -> ~2 iters).
__global__ __launch_bounds__(256) void gather256_combine(
        const ushort* __restrict__ feat,
        const int* __restrict__ ends,
        const int* __restrict__ col,
        const float* __restrict__ x0,
        float* __restrict__ outf,
        ushort* __restrict__ outb,
        int n) {
    int node = blockIdx.x * 4 + (threadIdx.x >> 6);
    if (node >= n) return;
    int lane = threadIdx.x & 63;
    int c = lane & 15, r = lane >> 4;          // c: 16B chunk of 256B row
    int beg = ends[node - 1];
    int end = ends[node];
    const ushort* fbase = feat + c * 8;

    float acc[8];
    #pragma unroll
    for (int j = 0; j < 8; ++j) acc[j] = 0.0f;

    for (int e = beg; e < end; e += 16) {
        int i0 = e + r, i1 = e + 4 + r, i2 = e + 8 + r, i3 = e + 12 + r;
        bool ok0 = i0 < end, ok1 = i1 < end, ok2 = i2 < end, ok3 = i3 < end;
        int nb0 = col[ok0 ? i0 : beg];
        int nb1 = col[ok1 ? i1 : beg];
        int nb2 = col[ok2 ? i2 : beg];
        int nb3 = col[ok3 ? i3 : beg];
        uint4 v0 = *(const uint4*)(fbase + (size_t)nb0 * 128);
        uint4 v1 = *(const uint4*)(fbase + (size_t)nb1 * 128);
        uint4 v2 = *(const uint4*)(fbase + (size_t)nb2 * 128);
        uint4 v3 = *(const uint4*)(fbase + (size_t)nb3 * 128);
        if (ok0) {
            acc[0] += bf16_lo(v0.x); acc[1] += bf16_hi(v0.x);
            acc[2] += bf16_lo(v0.y); acc[3] += bf16_hi(v0.y);
            acc[4] += bf16_lo(v0.z); acc[5] += bf16_hi(v0.z);
            acc[6] += bf16_lo(v0.w); acc[7] += bf16_hi(v0.w);
        }
        if (ok1) {
            acc[0] += bf16_lo(v1.x); acc[1] += bf16_hi(v1.x);
            acc[2] += bf16_lo(v1.y); acc[3] += bf16_hi(v1.y);
            acc[4] += bf16_lo(v1.z); acc[5] += bf16_hi(v1.z);
            acc[6] += bf16_lo(v1.w); acc[7] += bf16_hi(v1.w);
        }
        if (ok2) {
            acc[0] += bf16_lo(v2.x); acc[1] += bf16_hi(v2.x);
            acc[2] += bf16_lo(v2.y); acc[3] += bf16_hi(v2.y);
            acc[4] += bf16_lo(v2.z); acc[5] += bf16_hi(v2.z);
            acc[6] += bf16_lo(v2.w); acc[7] += bf16_hi(v2.w);
        }
        if (ok3) {
            acc[0] += bf16_lo(v3.x); acc[1] += bf16_hi(v3.x);
            acc[2] += bf16_lo(v3.y); acc[3] += bf16_hi(v3.y);
            acc[4] += bf16_lo(v3.z); acc[5] += bf16_hi(v3.z);
            acc[6] += bf16_lo(v3.w); acc[7] += bf16_hi(v3.w);
        }
    }
    // fold the 4 r-slots (lane bits 4,5)
    #pragma unroll
    for (int m = 16; m < 64; m <<= 1) {
        #pragma unroll
        for (int j = 0; j < 8; ++j) acc[j] += __shfl_xor(acc[j], m, 64);
    }
    // partner exchange: lane c (<8, u0-part) pairs with lane c+8 (u1-part, same elems)
    float b8[8];
    #pragma unroll
    for (int j = 0; j < 8; ++j) b8[j] = __shfl_xor(acc[j], 8, 64);

    if (r == 0 && c < 8) {
        int d = end - beg;
        float inv = (d > 0) ? 1.0f / (float)d : 0.0f;
        size_t base = (size_t)node * DIM + c * 8;
        float4 xa = *(const float4*)(x0 + base);
        float4 xb = *(const float4*)(x0 + base + 4);
        float i1v[8];
        #pragma unroll
        for (int j = 0; j < 8; ++j) i1v[j] = acc[j] * inv;
        float4 oa, ob;
        oa.x = (xa.x + i1v[0] + b8[0] * inv) * (1.0f / 3.0f);
        oa.y = (xa.y + i1v[1] + b8[1] * inv) * (1.0f / 3.0f);
        oa.z = (xa.z + i1v[2] + b8[2] * inv) * (1.0f / 3.0f);
        oa.w = (xa.w + i1v[3] + b8[3] * inv) * (1.0f / 3.0f);
        ob.x = (xb.x + i1v[4] + b8[4] * inv) * (1.0f / 3.0f);
        ob.y = (xb.y + i1v[5] + b8[5] * inv) * (1.0f / 3.0f);
        ob.z = (xb.z + i1v[6] + b8[6] * inv) * (1.0f / 3.0f);
        ob.w = (xb.w + i1v[7] + b8[7] * inv) * (1.0f / 3.0f);
        *(float4*)(outf + base)     = oa;
        *(float4*)(outf + base + 4) = ob;
        uint4 q;
        q.x = f2b(i1v[0]) | (f2b(i1v[1]) << 16);
        q.y = f2b(i1v[2]) | (f2b(i1v[3]) << 16);
        q.z = f2b(i1v[4]) | (f2b(i1v[5]) << 16);
        q.w = f2b(i1v[6]) | (f2b(i1v[7]) << 16);
        *(uint4*)(outb + base) = q;
    }
}

extern "C" void kernel_launch(void* const* d_in, const int* in_sizes, int n_in,
                              void* d_out, int out_size, void* d_ws, size_t ws_size,
                              hipStream_t stream) {
    const float* u0  = (const float*)d_in[0];
    const float* i0  = (const float*)d_in[1];
    const int*   src = (const int*)d_in[2];
    const int*   dst = (const int*)d_in[3];

    const int n_users = in_sizes[0] / DIM;   // 200000
    const int n_items = in_sizes[1] / DIM;   // 100000
    const int E       = in_sizes[2];         // 3000000
    const int n_nodes = n_users + n_items;
    const int nu_pb   = (n_users + NBK - 1) / NBK;   // 391 (< 2^9: packing req)
    const int ni_pb   = (n_items + NBK - 1) / NBK;   // 196 (< 2^8: packing req)

    const size_t u_elems = (size_t)n_users * DIM;
    const size_t i_elems = (size_t)n_items * DIM;

    // Workspace (~38 MB):
    //   deg[n_nodes+1] | btot[1024] | bstart[1025+pad] | col[2E] | ib[i_elems bf16]
    int* deg    = (int*)d_ws;
    int* btot   = deg + n_nodes + 1;
    int* bstart = btot + 1024;
    int* col    = bstart + 1028;
    ushort* ib  = (ushort*)(col + 2 * (size_t)E);  // i0 bf16, later i1 bf16

    // d_out: user region doubles as the per-tile offset table (6.1 MB) during
    // CSR build, then as u01 (u0|u1 interleaved bf16, 256B rows). item region
    // (out_i, 25.6 MB) doubles as the slab array (23.4 MB) — dead until
    // gather256_combine writes it.
    float* out_u = (float*)d_out;
    float* out_i = out_u + u_elems;
    ushort* u01  = (ushort*)d_out;         // exactly overlays out_u (51.2 MB)
    int*   table = (int*)d_out;
    uint*  bins  = (uint*)out_i;

    const int BLK = 256;
    const int ntiles = (E + BLK * TEPT - 1) / (BLK * TEPT);   // 1465

    // ---- CSR build: bin -> bucket sums -> bucket scan -> hist -> place ----
    bin_chunked<<<ntiles, BLK, 0, stream>>>(src, dst, table, bins,
                                            E, n_users, nu_pb, ni_pb);
    bucket_sums<<<2 * NBK, BLK, 0, stream>>>(table, btot, ntiles);
    scan1024<<<1, 1024, 0, stream>>>(btot, bstart, deg, n_nodes, 2 * E);
    fill_hist<<<2 * NBK, BLK, 0, stream>>>(bins, table, bstart, deg,
                                           n_users, n_items, ntiles, nu_pb, ni_pb);
    fill_place<<<2 * NBK, BLK, 0, stream>>>(bins, table, bstart, deg, col,
                                            n_users, n_items, ntiles, nu_pb, ni_pb);
    // deg holds exclusive starts (users then items), deg[n_nodes] = 2E.

    // ---- stage bf16 (table/bins regions are dead from here on) ----
    cvt_bf16_pitch<<<(int)((u_elems / 8 + BLK - 1) / BLK), BLK, 0, stream>>>(
        u0, u01, (int)(u_elems / 8), 128, 0);
    cvt_bf16_pitch<<<(int)((i_elems / 8 + BLK - 1) / BLK), BLK, 0, stream>>>(
        i0, ib, (int)(i_elems / 8), 64, 0);

    const int ug = (n_users + 3) / 4;
    const int ig = (n_items + 3) / 4;

    // ---- Pass A: u1 = mean(i0-nbrs) -> u01 odd halves (bf16) ----
    gather128<0><<<ug, BLK, 0, stream>>>(ib, deg + 1, col, nullptr,
                                         nullptr, 0, 0, nullptr,
                                         u01, 128, 64, n_users);

    // ---- Pass C: fused item pass: out_i = (i0 + i1 + i2)/3, ib <- bf16(i1) ----
    gather256_combine<<<ig, BLK, 0, stream>>>(u01, deg + n_users + 1, col,
                                              i0, out_i, ib, n_items);

    // ---- Pass D: out_u = (u0 + u1 + mean(i1-nbrs))/3 (u1 from u01 odd) ----
    gather128<1><<<ug, BLK, 0, stream>>>(ib, deg + 1, col, u0,
                                         u01, 128, 64, out_u,
                                         nullptr, 0, 0, n_users);
}

// Round 10
// 538.294 us; speedup vs baseline: 1.0735x; 1.0690x over previous
//
#include <hip/hip_runtime.h>

#define DIM 64
#define NBK 512       // node buckets per side (users / items)
#define TEPT 8        // edges per thread in bin_chunked (tile = 2048 edges)
#define TSTRIDE 1040  // table row stride in ints (1025 used, 64B-aligned rows)
#define LDSBUF 7168   // fill_place staged col entries (28 KB); mean 5860, +17 sigma

typedef unsigned int uint;
typedef unsigned short ushort;

// XCD-chunked bucket swizzle (T1): blockIdx -> bucket such that buckets
// 0..127 land on XCD 0, 128..255 on XCD 1, ... (HW dispatch is round-robin
// blockIdx%8). A 64B slab line spans ~4 consecutive buckets' slices; chunking
// makes those 4 buckets co-resident in ONE XCD L2 -> ~4x less L3 traffic.
// 1024 = 8*128 exactly -> bijective.
__device__ __forceinline__ int bswz(int bid) {
    return (bid & 7) * 128 + (bid >> 3);
}

// ---- bf16 helpers ----
__device__ __forceinline__ float bf16_lo(uint u) {
    union { uint u; float f; } c; c.u = u << 16; return c.f;
}
__device__ __forceinline__ float bf16_hi(uint u) {
    union { uint u; float f; } c; c.u = u & 0xffff0000u; return c.f;
}
__device__ __forceinline__ uint f2b(float f) {   // bf16 in low 16 bits (RNE)
    union { float f; uint u; } c; c.f = f;
    return (c.u + 0x7fffu + ((c.u >> 16) & 1u)) >> 16;
}

// f32 -> bf16, 8 elems/thread, output row pitch/offset in ushorts (rows of 64).
__global__ void cvt_bf16_pitch(const float* __restrict__ in, ushort* __restrict__ out,
                               int n8, int pitch, int off) {
    int k = blockIdx.x * blockDim.x + threadIdx.x;
    if (k >= n8) return;
    int row = k >> 3, g = k & 7;
    const float4* p = (const float4*)in + (size_t)k * 2;
    float4 a = p[0], b = p[1];
    uint4 o;
    o.x = f2b(a.x) | (f2b(a.y) << 16);
    o.y = f2b(a.z) | (f2b(a.w) << 16);
    o.z = f2b(b.x) | (f2b(b.y) << 16);
    o.w = f2b(b.z) | (f2b(b.w) << 16);
    *(uint4*)(out + (size_t)row * pitch + off + g * 8) = o;
}

// ---- CSR build, chunked-slab design, ZERO global atomics ----
// One pass over the edge list. Per tile (2048 edges -> 4096 entries):
//  - LDS per-bucket counts (1024 buckets: 512 user node-ranges + 512 item)
//  - parallel LDS exclusive scan -> bucket-grouped layout inside the tile's
//    OWN contiguous 16 KB slab (zero write amplification, no global cursors)
//  - per-tile 1025-int offset table row (coalesced)
// Entry words: user: (s % nu_pb) | t<<9 (391<2^9, t<2^17 -> 26b)
//              item: (t % ni_pb) | s<<8 (196<2^8, s<2^18 -> 26b)
__global__ __launch_bounds__(256) void bin_chunked(
        const int* __restrict__ src, const int* __restrict__ dst,
        int* __restrict__ table, uint* __restrict__ bins,
        int E, int n_users, int nu_pb, int ni_pb) {
    __shared__ int cnt[2 * NBK];
    __shared__ int lbase[2 * NBK + 1];
    __shared__ int ws[4];
    __shared__ uint ord[4096];
    for (int i = threadIdx.x; i < 2 * NBK; i += 256) cnt[i] = 0;
    __syncthreads();
    int t0 = blockIdx.x * (256 * TEPT) + threadIdx.x;
    uint st[2 * TEPT];   // packed (bucket<<12 | local offset), static idx only
    #pragma unroll
    for (int k = 0; k < TEPT; ++k) {
        int e = t0 + k * 256;
        if (e < E) {
            int s = src[e], t = dst[e];
            int bu = s / nu_pb;
            int bi = t / ni_pb;
            int ou = atomicAdd(&cnt[bu], 1);
            int oi = atomicAdd(&cnt[NBK + bi], 1);
            st[2 * k]     = ((uint)bu << 12) | (uint)ou;
            st[2 * k + 1] = ((uint)(NBK + bi) << 12) | (uint)oi;
        }
    }
    __syncthreads();
    // parallel exclusive scan of cnt[0..1024): 4 elems per thread
    {
        int c0 = threadIdx.x * 4;
        int a0 = cnt[c0], a1 = cnt[c0 + 1], a2 = cnt[c0 + 2], a3 = cnt[c0 + 3];
        int s4 = a0 + a1 + a2 + a3;
        int lane = threadIdx.x & 63, wid = threadIdx.x >> 6;
        int incl = s4;
        #pragma unroll
        for (int off = 1; off < 64; off <<= 1) {
            int t = __shfl_up(incl, off, 64);
            if (lane >= off) incl += t;
        }
        if (lane == 63) ws[wid] = incl;
        __syncthreads();
        int woff = 0;
        for (int w = 0; w < wid; ++w) woff += ws[w];
        int run = woff + incl - s4;
        lbase[c0] = run; run += a0;
        lbase[c0 + 1] = run; run += a1;
        lbase[c0 + 2] = run; run += a2;
        lbase[c0 + 3] = run; run += a3;
        if (threadIdx.x == 255) lbase[2 * NBK] = run;
    }
    __syncthreads();
    int* trow = table + (size_t)blockIdx.x * TSTRIDE;
    for (int i = threadIdx.x; i <= 2 * NBK; i += 256) trow[i] = lbase[i];
    // phase 2: re-read edges (L1-warm), place into bucket-grouped LDS
    #pragma unroll
    for (int k = 0; k < TEPT; ++k) {
        int e = t0 + k * 256;
        if (e < E) {
            int s = src[e], t = dst[e];
            uint su = st[2 * k], si = st[2 * k + 1];
            int bu = (int)(su >> 12);
            int bi = (int)(si >> 12) - NBK;
            uint wu = (uint)(s - bu * nu_pb) | ((uint)t << 9);
            uint wi = (uint)(t - bi * ni_pb) | ((uint)s << 8);
            ord[lbase[bu] + (int)(su & 4095u)] = wu;
            ord[lbase[NBK + bi] + (int)(si & 4095u)] = wi;
        }
    }
    __syncthreads();
    int tot = lbase[2 * NBK];
    uint* slab = bins + (size_t)blockIdx.x * 4096;
    for (int j = threadIdx.x; j < tot; j += 256)
        slab[j] = ord[j];
}

// Per-bucket edge totals from the per-tile table (L3-resident).
__global__ __launch_bounds__(256) void bucket_sums(
        const int* __restrict__ table, int* __restrict__ btot, int ntiles) {
    int b = bswz(blockIdx.x);   // 0..1023, XCD-chunked
    int s = 0;
    for (int t = threadIdx.x; t < ntiles; t += 256) {
        const int* row = table + (size_t)t * TSTRIDE + b;
        s += row[1] - row[0];
    }
    #pragma unroll
    for (int m = 1; m < 64; m <<= 1) s += __shfl_xor(s, m, 64);
    __shared__ int ws[4];
    int lane = threadIdx.x & 63, wid = threadIdx.x >> 6;
    if (lane == 0) ws[wid] = s;
    __syncthreads();
    if (threadIdx.x == 0) btot[b] = ws[0] + ws[1] + ws[2] + ws[3];
}

// Exclusive scan of the 1024 bucket totals -> bucket col bases. Also seals
// deg[n_nodes] = 2E.
__global__ void scan1024(const int* __restrict__ btot, int* __restrict__ bstart,
                         int* __restrict__ deg, int n_nodes, int total) {
    __shared__ int ws[16];
    int lane = threadIdx.x & 63, wid = threadIdx.x >> 6;
    int v = btot[threadIdx.x];
    int incl = v;
    #pragma unroll
    for (int off = 1; off < 64; off <<= 1) {
        int t = __shfl_up(incl, off, 64);
        if (lane >= off) incl += t;
    }
    if (lane == 63) ws[wid] = incl;
    __syncthreads();
    int woff = 0;
    for (int w = 0; w < wid; ++w) woff += ws[w];
    bstart[threadIdx.x] = woff + incl - v;
    if ((int)threadIdx.x == 1023) {
        bstart[1024] = total;
        deg[n_nodes] = total;
    }
}

// Histogram half of the fill: tiny LDS (1.6 KB) -> high occupancy for the
// latency-bound table/slab walk. Per-node degree histogram via LDS atomics;
// in-LDS chunked scan; deg written DENSE.
__global__ __launch_bounds__(256) void fill_hist(
        const uint* __restrict__ bins, const int* __restrict__ table,
        const int* __restrict__ bstart, int* __restrict__ deg,
        int n_users, int n_items, int ntiles, int nu_pb, int ni_pb) {
    __shared__ int cur[400];
    __shared__ int ws[4];
    int b = bswz(blockIdx.x);
    bool user = b < NBK;
    int bb = user ? b : b - NBK;
    int npb = user ? nu_pb : ni_pb;
    int ncnt = user ? n_users : n_items;
    int node0 = bb * npb;
    int nn = min(npb, ncnt - node0);
    if (nn <= 0) return;
    int idx0 = (user ? 0 : n_users) + node0;
    int colbase = bstart[b];
    uint mask = user ? 511u : 255u;

    for (int i = threadIdx.x; i < nn; i += 256) cur[i] = 0;
    __syncthreads();
    for (int t = threadIdx.x; t < ntiles; t += 256) {
        const int* row = table + (size_t)t * TSTRIDE + b;
        int a = row[0], e2 = row[1];
        const uint* slab = bins + (size_t)t * 4096;
        for (int j = a; j < e2; ++j)
            atomicAdd(&cur[(int)(slab[j] & mask)], 1);
    }
    __syncthreads();
    // chunked exclusive scan of cur[0..nn) -> dense deg write
    int CH = (nn + 255) >> 8;
    int c0 = threadIdx.x * CH;
    int s = 0;
    for (int i = 0; i < CH; ++i) {
        int idx = c0 + i;
        if (idx < nn) s += cur[idx];
    }
    int lane = threadIdx.x & 63, wid = threadIdx.x >> 6;
    int incl = s;
    #pragma unroll
    for (int off = 1; off < 64; off <<= 1) {
        int t = __shfl_up(incl, off, 64);
        if (lane >= off) incl += t;
    }
    if (lane == 63) ws[wid] = incl;
    __syncthreads();
    int woff = 0;
    for (int w = 0; w < wid; ++w) woff += ws[w];
    int running = woff + incl - s;
    for (int i = 0; i < CH; ++i) {
        int idx = c0 + i;
        if (idx < nn) {
            deg[idx0 + idx] = colbase + running;
            running += cur[idx];
        }
    }
}

// Placement half: local cursors rebuilt from deg (dense, L2-hot), entries
// placed via LDS cursor atomics into a staged 28 KB col segment, written out
// dense -> zero write amplification.
__global__ __launch_bounds__(256) void fill_place(
        const uint* __restrict__ bins, const int* __restrict__ table,
        const int* __restrict__ bstart, const int* __restrict__ deg,
        int* __restrict__ col,
        int n_users, int n_items, int ntiles, int nu_pb, int ni_pb) {
    __shared__ int cur[400];
    __shared__ int lbuf[LDSBUF];
    int b = bswz(blockIdx.x);
    bool user = b < NBK;
    int bb = user ? b : b - NBK;
    int npb = user ? nu_pb : ni_pb;
    int ncnt = user ? n_users : n_items;
    int node0 = bb * npb;
    int nn = min(npb, ncnt - node0);
    if (nn <= 0) return;
    int idx0 = (user ? 0 : n_users) + node0;
    int colbase = bstart[b];
    int nedge = bstart[b + 1] - colbase;
    uint mask = user ? 511u : 255u;
    int shift = user ? 9 : 8;

    for (int i = threadIdx.x; i < nn; i += 256)
        cur[i] = deg[idx0 + i] - colbase;
    __syncthreads();
    if (nedge <= LDSBUF) {
        for (int t = threadIdx.x; t < ntiles; t += 256) {
            const int* row = table + (size_t)t * TSTRIDE + b;
            int a = row[0], e2 = row[1];
            const uint* slab = bins + (size_t)t * 4096;
            for (int j = a; j < e2; ++j) {
                uint w = slab[j];
                int p = atomicAdd(&cur[(int)(w & mask)], 1);
                lbuf[p] = (int)(w >> shift);
            }
        }
        __syncthreads();
        for (int j = threadIdx.x; j < nedge; j += 256)
            col[colbase + j] = lbuf[j];
    } else {  // statistically unreachable fallback (bucket > LDSBUF edges)
        for (int t = threadIdx.x; t < ntiles; t += 256) {
            const int* row = table + (size_t)t * TSTRIDE + b;
            int a = row[0], e2 = row[1];
            const uint* slab = bins + (size_t)t * 4096;
            for (int j = a; j < e2; ++j) {
                uint w = slab[j];
                int p = atomicAdd(&cur[(int)(w & mask)], 1);
                col[colbase + p] = (int)(w >> shift);
            }
        }
    }
}

// ---- 128B-row gather (one wave per node; r=lane>>3 row slot, c=lane&7 chunk).
// 4 row-loads in flight (slots r, 8+r, 16+r, 24+r; mean degree 15 -> 1 iter).
// Masked slots load col[beg] -> wave-broadcast single line (cheap). Per-lane
// accumulation order identical to the 2-deep version (bitwise-same results).
// ends[node] = start of node+1 (pass deg+1); ends[node-1] = start of node.
// COMBINE=0: bf16 out at (ob_pitch, ob_off).
// COMBINE=1: outf = (x0 + x1 + mean)/3, x1 bf16 at (x1_pitch, x1_off).
// NOTE: outf may alias x1's buffer (same row, same wave) — data dependency
// (store value uses loaded x1) keeps this safe; no __restrict__ on those.
template <int COMBINE>
__global__ __launch_bounds__(256) void gather128(
        const ushort* __restrict__ feat,
        const int* __restrict__ ends,
        const int* __restrict__ col,
        const float* __restrict__ x0,
        const ushort* x1, int x1_pitch, int x1_off,
        float* outf,
        ushort* outb, int ob_pitch, int ob_off,
        int n) {
    int node = blockIdx.x * 4 + (threadIdx.x >> 6);
    if (node >= n) return;
    int lane = threadIdx.x & 63;
    int r = lane >> 3, c = lane & 7;
    int beg = ends[node - 1];
    int end = ends[node];
    const ushort* fbase = feat + c * 8;

    float acc[8];
    #pragma unroll
    for (int j = 0; j < 8; ++j) acc[j] = 0.0f;

    for (int e = beg; e < end; e += 32) {
        int i0 = e + r, i1 = e + 8 + r, i2 = e + 16 + r, i3 = e + 24 + r;
        bool ok0 = i0 < end, ok1 = i1 < end, ok2 = i2 < end, ok3 = i3 < end;
        int nb0 = col[ok0 ? i0 : beg];
        int nb1 = col[ok1 ? i1 : beg];
        int nb2 = col[ok2 ? i2 : beg];
        int nb3 = col[ok3 ? i3 : beg];
        uint4 v0 = *(const uint4*)(fbase + (size_t)nb0 * DIM);
        uint4 v1 = *(const uint4*)(fbase + (size_t)nb1 * DIM);
        uint4 v2 = *(const uint4*)(fbase + (size_t)nb2 * DIM);
        uint4 v3 = *(const uint4*)(fbase + (size_t)nb3 * DIM);
        if (ok0) {
            acc[0] += bf16_lo(v0.x); acc[1] += bf16_hi(v0.x);
            acc[2] += bf16_lo(v0.y); acc[3] += bf16_hi(v0.y);
            acc[4] += bf16_lo(v0.z); acc[5] += bf16_hi(v0.z);
            acc[6] += bf16_lo(v0.w); acc[7] += bf16_hi(v0.w);
        }
        if (ok1) {
            acc[0] += bf16_lo(v1.x); acc[1] += bf16_hi(v1.x);
            acc[2] += bf16_lo(v1.y); acc[3] += bf16_hi(v1.y);
            acc[4] += bf16_lo(v1.z); acc[5] += bf16_hi(v1.z);
            acc[6] += bf16_lo(v1.w); acc[7] += bf16_hi(v1.w);
        }
        if (ok2) {
            acc[0] += bf16_lo(v2.x); acc[1] += bf16_hi(v2.x);
            acc[2] += bf16_lo(v2.y); acc[3] += bf16_hi(v2.y);
            acc[4] += bf16_lo(v2.z); acc[5] += bf16_hi(v2.z);
            acc[6] += bf16_lo(v2.w); acc[7] += bf16_hi(v2.w);
        }
        if (ok3) {
            acc[0] += bf16_lo(v3.x); acc[1] += bf16_hi(v3.x);
            acc[2] += bf16_lo(v3.y); acc[3] += bf16_hi(v3.y);
            acc[4] += bf16_lo(v3.z); acc[5] += bf16_hi(v3.z);
            acc[6] += bf16_lo(v3.w); acc[7] += bf16_hi(v3.w);
        }
    }
    #pragma unroll
    for (int m = 8; m < 64; m <<= 1) {
        #pragma unroll
        for (int j = 0; j < 8; ++j) acc[j] += __shfl_xor(acc[j], m, 64);
    }
    if (r == 0) {
        int d = end - beg;
        float inv = (d > 0) ? 1.0f / (float)d : 0.0f;
        if (COMBINE) {
            size_t base = (size_t)node * DIM + c * 8;
            float4 xa = *(const float4*)(x0 + base);
            float4 xb = *(const float4*)(x0 + base + 4);
            uint4  xq = *(const uint4*)(x1 + (size_t)node * x1_pitch + x1_off + c * 8);
            float4 oa, ob;
            oa.x = (xa.x + bf16_lo(xq.x) + acc[0] * inv) * (1.0f / 3.0f);
            oa.y = (xa.y + bf16_hi(xq.x) + acc[1] * inv) * (1.0f / 3.0f);
            oa.z = (xa.z + bf16_lo(xq.y) + acc[2] * inv) * (1.0f / 3.0f);
            oa.w = (xa.w + bf16_hi(xq.y) + acc[3] * inv) * (1.0f / 3.0f);
            ob.x = (xb.x + bf16_lo(xq.z) + acc[4] * inv) * (1.0f / 3.0f);
            ob.y = (xb.y + bf16_hi(xq.z) + acc[5] * inv) * (1.0f / 3.0f);
            ob.z = (xb.z + bf16_lo(xq.w) + acc[6] * inv) * (1.0f / 3.0f);
            ob.w = (xb.w + bf16_hi(xq.w) + acc[7] * inv) * (1.0f / 3.0f);
            *(float4*)(outf + base)     = oa;
            *(float4*)(outf + base + 4) = ob;
        } else {
            uint4 o;
            o.x = f2b(acc[0] * inv) | (f2b(acc[1] * inv) << 16);
            o.y = f2b(acc[2] * inv) | (f2b(acc[3] * inv) << 16);
            o.z = f2b(acc[4] * inv) | (f2b(acc[5] * inv) << 16);
            o.w = f2b(acc[6] * inv) | (f2b(acc[7] * inv) << 16);
            *(uint4*)(outb + (size_t)node * ob_pitch + ob_off + c * 8) = o;
        }
    }
}

// ---- 256B-row fused item pass: feat = u01 (u0|u1 interleaved, pitch 128).
// Computes i1 = mean(u0-nbrs), i2 = mean(u1-nbrs) in ONE col walk.
// outf = (x0 + i1 + i2)/3 (f32), outb = bf16(i1) (dense pitch 64).
// 4 row-loads in flight per iteration (mean degree 30 -> ~2 iters).
__global__ __launch_bounds__(256) void gather256_combine(
        const ushort* __restrict__ feat,
        const int* __restrict__ ends,
        const int* __restrict__ col,
        const float* __restrict__ x0,
        float* __restrict__ outf,
        ushort* __restrict__ outb,
        int n) {
    int node = blockIdx.x * 4 + (threadIdx.x >> 6);
    if (node >= n) return;
    int lane = threadIdx.x & 63;
    int c = lane & 15, r = lane >> 4;          // c: 16B chunk of 256B row
    int beg = ends[node - 1];
    int end = ends[node];
    const ushort* fbase = feat + c * 8;

    float acc[8];
    #pragma unroll
    for (int j = 0; j < 8; ++j) acc[j] = 0.0f;

    for (int e = beg; e < end; e += 16) {
        int i0 = e + r, i1 = e + 4 + r, i2 = e + 8 + r, i3 = e + 12 + r;
        bool ok0 = i0 < end, ok1 = i1 < end, ok2 = i2 < end, ok3 = i3 < end;
        int nb0 = col[ok0 ? i0 : beg];
        int nb1 = col[ok1 ? i1 : beg];
        int nb2 = col[ok2 ? i2 : beg];
        int nb3 = col[ok3 ? i3 : beg];
        uint4 v0 = *(const uint4*)(fbase + (size_t)nb0 * 128);
        uint4 v1 = *(const uint4*)(fbase + (size_t)nb1 * 128);
        uint4 v2 = *(const uint4*)(fbase + (size_t)nb2 * 128);
        uint4 v3 = *(const uint4*)(fbase + (size_t)nb3 * 128);
        if (ok0) {
            acc[0] += bf16_lo(v0.x); acc[1] += bf16_hi(v0.x);
            acc[2] += bf16_lo(v0.y); acc[3] += bf16_hi(v0.y);
            acc[4] += bf16_lo(v0.z); acc[5] += bf16_hi(v0.z);
            acc[6] += bf16_lo(v0.w); acc[7] += bf16_hi(v0.w);
        }
        if (ok1) {
            acc[0] += bf16_lo(v1.x); acc[1] += bf16_hi(v1.x);
            acc[2] += bf16_lo(v1.y); acc[3] += bf16_hi(v1.y);
            acc[4] += bf16_lo(v1.z); acc[5] += bf16_hi(v1.z);
            acc[6] += bf16_lo(v1.w); acc[7] += bf16_hi(v1.w);
        }
        if (ok2) {
            acc[0] += bf16_lo(v2.x); acc[1] += bf16_hi(v2.x);
            acc[2] += bf16_lo(v2.y); acc[3] += bf16_hi(v2.y);
            acc[4] += bf16_lo(v2.z); acc[5] += bf16_hi(v2.z);
            acc[6] += bf16_lo(v2.w); acc[7] += bf16_hi(v2.w);
        }
        if (ok3) {
            acc[0] += bf16_lo(v3.x); acc[1] += bf16_hi(v3.x);
            acc[2] += bf16_lo(v3.y); acc[3] += bf16_hi(v3.y);
            acc[4] += bf16_lo(v3.z); acc[5] += bf16_hi(v3.z);
            acc[6] += bf16_lo(v3.w); acc[7] += bf16_hi(v3.w);
        }
    }
    // fold the 4 r-slots (lane bits 4,5)
    #pragma unroll
    for (int m = 16; m < 64; m <<= 1) {
        #pragma unroll
        for (int j = 0; j < 8; ++j) acc[j] += __shfl_xor(acc[j], m, 64);
    }
    // partner exchange: lane c (<8, u0-part) pairs with lane c+8 (u1-part, same elems)
    float b8[8];
    #pragma unroll
    for (int j = 0; j < 8; ++j) b8[j] = __shfl_xor(acc[j], 8, 64);

    if (r == 0 && c < 8) {
        int d = end - beg;
        float inv = (d > 0) ? 1.0f / (float)d : 0.0f;
        size_t base = (size_t)node * DIM + c * 8;
        float4 xa = *(const float4*)(x0 + base);
        float4 xb = *(const float4*)(x0 + base + 4);
        float i1v[8];
        #pragma unroll
        for (int j = 0; j < 8; ++j) i1v[j] = acc[j] * inv;
        float4 oa, ob;
        oa.x = (xa.x + i1v[0] + b8[0] * inv) * (1.0f / 3.0f);
        oa.y = (xa.y + i1v[1] + b8[1] * inv) * (1.0f / 3.0f);
        oa.z = (xa.z + i1v[2] + b8[2] * inv) * (1.0f / 3.0f);
        oa.w = (xa.w + i1v[3] + b8[3] * inv) * (1.0f / 3.0f);
        ob.x = (xb.x + i1v[4] + b8[4] * inv) * (1.0f / 3.0f);
        ob.y = (xb.y + i1v[5] + b8[5] * inv) * (1.0f / 3.0f);
        ob.z = (xb.z + i1v[6] + b8[6] * inv) * (1.0f / 3.0f);
        ob.w = (xb.w + i1v[7] + b8[7] * inv) * (1.0f / 3.0f);
        *(float4*)(outf + base)     = oa;
        *(float4*)(outf + base + 4) = ob;
        uint4 q;
        q.x = f2b(i1v[0]) | (f2b(i1v[1]) << 16);
        q.y = f2b(i1v[2]) | (f2b(i1v[3]) << 16);
        q.z = f2b(i1v[4]) | (f2b(i1v[5]) << 16);
        q.w = f2b(i1v[6]) | (f2b(i1v[7]) << 16);
        *(uint4*)(outb + base) = q;
    }
}

extern "C" void kernel_launch(void* const* d_in, const int* in_sizes, int n_in,
                              void* d_out, int out_size, void* d_ws, size_t ws_size,
                              hipStream_t stream) {
    const float* u0  = (const float*)d_in[0];
    const float* i0  = (const float*)d_in[1];
    const int*   src = (const int*)d_in[2];
    const int*   dst = (const int*)d_in[3];

    const int n_users = in_sizes[0] / DIM;   // 200000
    const int n_items = in_sizes[1] / DIM;   // 100000
    const int E       = in_sizes[2];         // 3000000
    const int n_nodes = n_users + n_items;
    const int nu_pb   = (n_users + NBK - 1) / NBK;   // 391 (< 2^9: packing req)
    const int ni_pb   = (n_items + NBK - 1) / NBK;   // 196 (< 2^8: packing req)

    const size_t u_elems = (size_t)n_users * DIM;
    const size_t i_elems = (size_t)n_items * DIM;

    // Workspace (~38 MB):
    //   deg[n_nodes+1] | btot[1024] | bstart[1025+pad] | col[2E] | ib[i_elems bf16]
    int* deg    = (int*)d_ws;
    int* btot   = deg + n_nodes + 1;
    int* bstart = btot + 1024;
    int* col    = bstart + 1028;
    ushort* ib  = (ushort*)(col + 2 * (size_t)E);  // i0 bf16, later i1 bf16

    // d_out: user region doubles as the per-tile offset table (6.1 MB) during
    // CSR build, then as u01 (u0|u1 interleaved bf16, 256B rows). item region
    // (out_i, 25.6 MB) doubles as the slab array (23.4 MB) — dead until
    // gather256_combine writes it.
    float* out_u = (float*)d_out;
    float* out_i = out_u + u_elems;
    ushort* u01  = (ushort*)d_out;         // exactly overlays out_u (51.2 MB)
    int*   table = (int*)d_out;
    uint*  bins  = (uint*)out_i;

    const int BLK = 256;
    const int ntiles = (E + BLK * TEPT - 1) / (BLK * TEPT);   // 1465

    // ---- CSR build: bin -> bucket sums -> bucket scan -> hist -> place ----
    bin_chunked<<<ntiles, BLK, 0, stream>>>(src, dst, table, bins,
                                            E, n_users, nu_pb, ni_pb);
    bucket_sums<<<2 * NBK, BLK, 0, stream>>>(table, btot, ntiles);
    scan1024<<<1, 1024, 0, stream>>>(btot, bstart, deg, n_nodes, 2 * E);
    fill_hist<<<2 * NBK, BLK, 0, stream>>>(bins, table, bstart, deg,
                                           n_users, n_items, ntiles, nu_pb, ni_pb);
    fill_place<<<2 * NBK, BLK, 0, stream>>>(bins, table, bstart, deg, col,
                                            n_users, n_items, ntiles, nu_pb, ni_pb);
    // deg holds exclusive starts (users then items), deg[n_nodes] = 2E.

    // ---- stage bf16 (table/bins regions are dead from here on) ----
    cvt_bf16_pitch<<<(int)((u_elems / 8 + BLK - 1) / BLK), BLK, 0, stream>>>(
        u0, u01, (int)(u_elems / 8), 128, 0);
    cvt_bf16_pitch<<<(int)((i_elems / 8 + BLK - 1) / BLK), BLK, 0, stream>>>(
        i0, ib, (int)(i_elems / 8), 64, 0);

    const int ug = (n_users + 3) / 4;
    const int ig = (n_items + 3) / 4;

    // ---- Pass A: u1 = mean(i0-nbrs) -> u01 odd halves (bf16) ----
    gather128<0><<<ug, BLK, 0, stream>>>(ib, deg + 1, col, nullptr,
                                         nullptr, 0, 0, nullptr,
                                         u01, 128, 64, n_users);

    // ---- Pass C: fused item pass: out_i = (i0 + i1 + i2)/3, ib <- bf16(i1) ----
    gather256_combine<<<ig, BLK, 0, stream>>>(u01, deg + n_users + 1, col,
                                              i0, out_i, ib, n_items);

    // ---- Pass D: out_u = (u0 + u1 + mean(i1-nbrs))/3 (u1 from u01 odd) ----
    gather128<1><<<ug, BLK, 0, stream>>>(ib, deg + 1, col, u0,
                                         u01, 128, 64, out_u,
                                         nullptr, 0, 0, n_users);
}